// Round 1
// baseline (1836.210 us; speedup 1.0000x reference)
//
#include <hip/hip_runtime.h>
#include <cstdint>
#include <cmath>

#define Bsz  1024
#define Pdim 1024
#define Hdim 4096
#define Ndim 32
#define Ddim 512
#define Ktop 128

// ---------------------------------------------------------------------------
// Kernel 1: proximal GEMM  out[b,h] = dot(pin[b,:], W[h,:]) + bias[h]
// tile: BM=32 (b) x BN=256 (h), BK=32, 256 threads (4 waves)
// wave wv owns b = b0 + 8*wv + i (i=0..7); lane l owns h = h0 + 4*l + j (j=0..3)
// ---------------------------------------------------------------------------
__global__ __launch_bounds__(256) void proximal_gemm(
    const float* __restrict__ pin, const float* __restrict__ W,
    const float* __restrict__ bias, float* __restrict__ out)
{
  __shared__ float Blds[32 * 256];  // [k][h_rel]  32KB
  __shared__ float Alds[32 * 32];   // [k][b_rel]   4KB
  const int t  = threadIdx.x;
  const int l  = t & 63;
  const int wv = t >> 6;

  // 16 htiles x 32 btiles = 512 blocks; keep all btiles of an htile on one XCD
  const int ell   = blockIdx.x;
  const int xcd   = ell & 7;
  const int q     = ell >> 3;          // [0,64)
  const int htile = xcd * 2 + (q >> 5);
  const int btile = q & 31;
  const int h0 = htile * 256, b0 = btile * 32;

  float acc[8][4];
#pragma unroll
  for (int i = 0; i < 8; i++)
    for (int j = 0; j < 4; j++) acc[i][j] = 0.f;

  const float* wrow = W + (size_t)(h0 + t) * Pdim;
  const int ab = t >> 3, ak = (t & 7) * 4;
  const float* arow = pin + (size_t)(b0 + ab) * Pdim + ak;

  for (int kt = 0; kt < Pdim / 32; ++kt) {
    const int p0 = kt * 32;
    float wbuf[32];
#pragma unroll
    for (int f = 0; f < 8; f++) {
      float4 v = *(const float4*)(wrow + p0 + f * 4);
      wbuf[f * 4 + 0] = v.x; wbuf[f * 4 + 1] = v.y;
      wbuf[f * 4 + 2] = v.z; wbuf[f * 4 + 3] = v.w;
    }
    float4 av = *(const float4*)(arow + p0);
    __syncthreads();  // previous-iteration LDS reads done
#pragma unroll
    for (int f = 0; f < 32; f++) Blds[f * 256 + t] = wbuf[f];
    Alds[(ak + 0) * 32 + ab] = av.x;
    Alds[(ak + 1) * 32 + ab] = av.y;
    Alds[(ak + 2) * 32 + ab] = av.z;
    Alds[(ak + 3) * 32 + ab] = av.w;
    __syncthreads();
#pragma unroll
    for (int k = 0; k < 32; k++) {
      float4 bv  = *(const float4*)&Blds[k * 256 + 4 * l];
      float4 alo = *(const float4*)&Alds[k * 32 + 8 * wv];
      float4 ahi = *(const float4*)&Alds[k * 32 + 8 * wv + 4];
      float a0[8] = {alo.x, alo.y, alo.z, alo.w, ahi.x, ahi.y, ahi.z, ahi.w};
#pragma unroll
      for (int i = 0; i < 8; i++) {
        acc[i][0] += a0[i] * bv.x;
        acc[i][1] += a0[i] * bv.y;
        acc[i][2] += a0[i] * bv.z;
        acc[i][3] += a0[i] * bv.w;
      }
    }
  }
  float4 bb = *(const float4*)(bias + h0 + 4 * l);
#pragma unroll
  for (int i = 0; i < 8; i++) {
    float4 o;
    o.x = acc[i][0] + bb.x;
    o.y = acc[i][1] + bb.y;
    o.z = acc[i][2] + bb.z;
    o.w = acc[i][3] + bb.w;
    *(float4*)(out + (size_t)(b0 + 8 * wv + i) * Hdim + h0 + 4 * l) = o;
  }
}

// ---------------------------------------------------------------------------
// Kernel 2: distal dendrite GEMM + abs-argmax over n + sigmoid gate (RMW out)
// B-matrix = distal reshaped (H*N, D), row n' = h*32+n.
// tile: BM=32 (b) x BN'=256 (n'), BK=32, 256 threads.
// lane l owns n'_rel = 4*l + j; wave wv owns b = b0 + 8*wv + i.
// ---------------------------------------------------------------------------
__global__ __launch_bounds__(256) void distal_gate(
    const float* __restrict__ din, const float* __restrict__ distal,
    float* __restrict__ out)
{
  __shared__ float Blds[32 * 256];  // [k][n'_rel] 32KB
  __shared__ float Alds[32 * 32];   // [k][b_rel]   4KB
  const int t  = threadIdx.x;
  const int l  = t & 63;
  const int wv = t >> 6;

  // 512 htiles x 32 btiles = 16384 blocks; 64 htiles per XCD so distal
  // streams from HBM once (reuse across btiles stays in that XCD's L2).
  const int ell   = blockIdx.x;
  const int xcd   = ell & 7;
  const int q     = ell >> 3;              // [0,2048)
  const int htile = xcd * 64 + (q >> 5);   // [0,512)
  const int btile = q & 31;
  const int n0 = htile * 256, b0 = btile * 32;

  float acc[8][4];
#pragma unroll
  for (int i = 0; i < 8; i++)
    for (int j = 0; j < 4; j++) acc[i][j] = 0.f;

  const float* brow = distal + (size_t)(n0 + t) * Ddim;
  const int ab = t >> 3, ak = (t & 7) * 4;
  const float* arow = din + (size_t)(b0 + ab) * Ddim + ak;

  for (int kt = 0; kt < Ddim / 32; ++kt) {
    const int d0 = kt * 32;
    float wbuf[32];
#pragma unroll
    for (int f = 0; f < 8; f++) {
      float4 v = *(const float4*)(brow + d0 + f * 4);
      wbuf[f * 4 + 0] = v.x; wbuf[f * 4 + 1] = v.y;
      wbuf[f * 4 + 2] = v.z; wbuf[f * 4 + 3] = v.w;
    }
    float4 av = *(const float4*)(arow + d0);
    __syncthreads();
#pragma unroll
    for (int f = 0; f < 32; f++) Blds[f * 256 + t] = wbuf[f];
    Alds[(ak + 0) * 32 + ab] = av.x;
    Alds[(ak + 1) * 32 + ab] = av.y;
    Alds[(ak + 2) * 32 + ab] = av.z;
    Alds[(ak + 3) * 32 + ab] = av.w;
    __syncthreads();
#pragma unroll
    for (int k = 0; k < 32; k++) {
      float4 bv  = *(const float4*)&Blds[k * 256 + 4 * l];
      float4 alo = *(const float4*)&Alds[k * 32 + 8 * wv];
      float4 ahi = *(const float4*)&Alds[k * 32 + 8 * wv + 4];
      float a0[8] = {alo.x, alo.y, alo.z, alo.w, ahi.x, ahi.y, ahi.z, ahi.w};
#pragma unroll
      for (int i = 0; i < 8; i++) {
        acc[i][0] += a0[i] * bv.x;
        acc[i][1] += a0[i] * bv.y;
        acc[i][2] += a0[i] * bv.z;
        acc[i][3] += a0[i] * bv.w;
      }
    }
  }

  // abs-argmax over n (32 values = 8 lanes x 4 regs), numpy first-index ties.
  const int i0  = l & 7;   // b sub-index this lane will write
  const int grp = l >> 3;  // h_rel
  float v = 0.f;
#pragma unroll
  for (int bi = 0; bi < 8; bi++) {
    float bav = fabsf(acc[bi][0]);
    float bv_ = acc[bi][0];
    int   bn  = 4 * i0;
#pragma unroll
    for (int j = 1; j < 4; j++) {
      float av2 = fabsf(acc[bi][j]);
      if (av2 > bav) { bav = av2; bv_ = acc[bi][j]; bn = 4 * i0 + j; }
    }
#pragma unroll
    for (int m = 1; m < 8; m <<= 1) {
      float oav = __shfl_xor(bav, m, 64);
      float ov  = __shfl_xor(bv_, m, 64);
      int   on  = __shfl_xor(bn,  m, 64);
      if (oav > bav || (oav == bav && on < bn)) { bav = oav; bv_ = ov; bn = on; }
    }
    if (bi == i0) v = bv_;
  }
  const float g = 1.f / (1.f + expf(-v));
  const size_t idx = (size_t)(b0 + 8 * wv + i0) * Hdim + (size_t)htile * 8 + grp;
  out[idx] *= g;
}

// ---------------------------------------------------------------------------
// Kernel 3: per-row top-k mask (in place on out). One block per row.
// 256-bin MSB-first radix select on sign-flipped float keys; deterministic
// index-ordered tie inclusion.
// ---------------------------------------------------------------------------
__device__ __forceinline__ unsigned keyf(float f) {
  unsigned u = __float_as_uint(f);
  return (u & 0x80000000u) ? ~u : (u | 0x80000000u);
}

__global__ __launch_bounds__(256) void topk_mask(float* __restrict__ out)
{
  __shared__ float vals[Hdim];       // 16KB
  __shared__ unsigned hist[256];
  __shared__ unsigned sc[4];
  __shared__ unsigned s_prefix, s_kk;
  const int t = threadIdx.x;
  float* row = out + (size_t)blockIdx.x * Hdim;

#pragma unroll
  for (int qq = 0; qq < 4; qq++) {
    float4 v = *(const float4*)(row + qq * 1024 + t * 4);
    *(float4*)&vals[qq * 1024 + t * 4] = v;
  }
  if (t == 0) { s_prefix = 0u; s_kk = Ktop; }
  __syncthreads();

  for (int shift = 24; shift >= 0; shift -= 8) {
    hist[t] = 0u;  // exactly 256 threads
    __syncthreads();
    const unsigned prefix = s_prefix;
    const unsigned maskhi = (shift == 24) ? 0u : (0xFFFFFFFFu << (shift + 8));
    for (int c = 0; c < 16; c++) {
      unsigned u = keyf(vals[c * 256 + t]);
      if ((u & maskhi) == prefix)
        atomicAdd(&hist[(u >> shift) & 255u], 1u);
    }
    __syncthreads();
    if (t == 0) {
      unsigned kk = s_kk, cum = 0;
      int bin = 255;
      for (; bin > 0; --bin) {
        unsigned c = hist[bin];
        if (cum + c >= kk) break;
        cum += c;
      }
      s_kk = kk - cum;
      s_prefix = prefix | ((unsigned)bin << shift);
    }
    __syncthreads();
  }
  const unsigned T  = s_prefix;
  const unsigned kk = s_kk;  // number of ties at T to keep (>=1)

  const int lane = t & 63, w = t >> 6;
  unsigned running = 0;
  for (int c = 0; c < 16; c++) {
    const int h = c * 256 + t;
    const float v = vals[h];
    const unsigned u = keyf(v);
    const bool tie = (u == T);
    unsigned long long m = __ballot(tie);
    unsigned lpfx = (unsigned)__popcll(m & ((1ull << lane) - 1ull));
    if (lane == 0) sc[w] = (unsigned)__popcll(m);
    __syncthreads();
    unsigned off = 0;
#pragma unroll
    for (int ww = 0; ww < 4; ww++) if (ww < w) off += sc[ww];
    const unsigned rank = running + off + lpfx;
    row[h] = (u > T) ? v : ((tie && rank < kk) ? v : 0.f);
    const unsigned tot = sc[0] + sc[1] + sc[2] + sc[3];
    __syncthreads();
    running += tot;
  }
}

extern "C" void kernel_launch(void* const* d_in, const int* in_sizes, int n_in,
                              void* d_out, int out_size, void* d_ws, size_t ws_size,
                              hipStream_t stream)
{
  (void)in_sizes; (void)n_in; (void)d_ws; (void)ws_size; (void)out_size;
  const float* pin  = (const float*)d_in[0];  // (B,P)
  const float* dinp = (const float*)d_in[1];  // (B,D)
  const float* W    = (const float*)d_in[2];  // (H,P)
  const float* bias = (const float*)d_in[3];  // (H,)
  const float* dst  = (const float*)d_in[4];  // (H,N,D)
  float* out = (float*)d_out;                 // (B,H)

  hipLaunchKernelGGL(proximal_gemm, dim3(512),   dim3(256), 0, stream, pin, W, bias, out);
  hipLaunchKernelGGL(distal_gate,   dim3(16384), dim3(256), 0, stream, dinp, dst, out);
  hipLaunchKernelGGL(topk_mask,     dim3(Bsz),   dim3(256), 0, stream, out);
}